// Round 4
// baseline (210.914 us; speedup 1.0000x reference)
//
#include <hip/hip_runtime.h>
#include <hip/hip_fp16.h>
#include <math.h>

// ---------------- problem constants ----------------
// x: (16, 2048, 64) f32  -> out: (16, 2048, 64, 5) f32
// scales = {1,27,76,167,336}; morlet int_psi, n=1024, [-8,8]
#define NB    16
#define T     2048
#define NC    64
#define NROWS (NB*NC)     // 1024
#define PADL2 2696        // left zero-pad (halves), mult of 8
#define XSH_N 7440        // 2696 + 2048 + right pad; max valid B index 7439

// Unified global-k chunk axis: chunk c covers k in [32c, 32c+32), c in [0,169).
//   sl:      0      1      2      3      4
//   scale:   336    167    76     27     1
//   CLO:     0      42     65     77     83
//   KS2:     5408   2720   1248   480    64     (=32*NCH, W row stride)
//   WOFF:    0      86528  130048 150016 157696
//   outslot: 4      3      2      1      0
// alive: 336:[0,169) 167:[42,127) 76:[65,104) 27:[77,92) 1:[83,85)

// ws layout (bytes):
//   0        : __half W[158720]                    (~310 KB)
//   512 KB   : __half xT[1024][2048]               (4 MB)
//   512KB+4MB: __half outT2[16][128][64][5][16]    (20 MB)  [n][tb][c][s][tt]
#define WS_XT    (1u<<19)
#define WS_OUTT  ((1u<<19) + (1u<<22))

typedef _Float16 half8  __attribute__((ext_vector_type(8)));
typedef _Float16 half4v __attribute__((ext_vector_type(4)));
typedef float    f32x4  __attribute__((ext_vector_type(4)));

// ---------------- kernel 1: W-build (blocks 0..15, one per diagonal bb) ----------------
//                 + transpose (blocks 16..143)
// init replicates reference float64 arithmetic EXACTLY (verified rounds 1/2/4).
__global__ __launch_bounds__(1024) void cwt_prep(const float* __restrict__ x,
                                                 __half* __restrict__ xT,
                                                 __half* __restrict__ W) {
    __shared__ double ps[1024];
    __shared__ double sc[1024];
    __shared__ float  k32[1024];
    __shared__ float  tile4[4][64 * 65];
    const int tid = threadIdx.x;

    if (blockIdx.x < 16) {
        const int bb = blockIdx.x;
        constexpr int SCe[5]   = {336, 167, 76, 27, 1};
        constexpr int KS2[5]   = {5408, 2720, 1248, 480, 64};
        constexpr int WOFFe[5] = {0, 86528, 130048, 150016, 157696};
        constexpr int CLOe[5]  = {0, 42, 65, 77, 83};

        // zero-fill own rows only (19840 B per bb)
        {
            const uint4 z = make_uint4(0u, 0u, 0u, 0u);
            #pragma unroll
            for (int sl = 0; sl < 5; ++sl) {
                uint4* z4 = (uint4*)(W + WOFFe[sl] + bb * KS2[sl]);
                const int n8 = KS2[sl] / 8;
                for (int i = tid; i < n8; i += 1024) z4[i] = z;
            }
        }

        const double delta = 16.0 / 1023.0;
        double t = (tid == 1023) ? 8.0 : (-8.0 + delta * (double)tid);
        ps[tid] = exp(-0.5 * t * t) * cos(5.0 * t);
        __syncthreads();   // also orders the zero-fill before the scatter below

        double* a = ps; double* b = sc;
        for (int off = 1; off < 1024; off <<= 1) {
            double v = a[tid];
            if (tid >= off) v += a[tid - off];
            b[tid] = v;
            __syncthreads();
            double* tmp = a; a = b; b = tmp;
        }
        const double step = ((-8.0 + delta) + 8.0);   // NOT exactly 16/1023
        k32[tid] = (float)(a[tid] * step);
        __syncthreads();

        for (int sl = 0; sl < 5; ++sl) {
            const int s = SCe[sl];
            const int L = 16 * s + 1;
            const double c = (double)s * step;
            const float sq = (float)sqrt((double)s);
            const int posoff = PADL2 - 8 * s - 1;
            const int kb0 = posoff - 32 * CLOe[sl];
            __half* wb = W + WOFFe[sl];
            const int Ks = KS2[sl];
            for (int i = tid; i <= L; i += 1024) {
                float g; bool wr = true;
                if (i == 0) {
                    g = sq * k32[0];
                } else if (i == L) {
                    long long jl = (long long)((double)(L - 1) / c);
                    if (jl > 1023) jl = 1023;
                    g = -sq * k32[jl];
                } else {
                    long long j1 = (long long)((double)i / c);
                    long long j0 = (long long)((double)(i - 1) / c);
                    if (j1 > 1023) j1 = 1023;
                    if (j0 > 1023) j0 = 1023;
                    wr = (j1 > j0);
                    g = sq * (k32[j1] - k32[j0]);
                }
                if (wr) {
                    wb[bb * Ks + kb0 + i + bb] = __float2half(g);
                }
            }
        }
    } else {
        const int g    = tid >> 8;                // 0..3: tile within block
        const int t256 = tid & 255;
        const int ti   = (blockIdx.x - 16) * 4 + g;  // 0..511
        const int n    = ti >> 5;
        const int t0   = (ti & 31) << 6;
        float* tl = tile4[g];

        const float4* src = (const float4*)(x + ((size_t)(n * T + t0)) * NC);
        #pragma unroll
        for (int k = 0; k < 4; ++k) {
            float4 v = src[t256 + 256 * k];
            const int flat = (t256 + 256 * k) * 4;
            const int tt = flat >> 6, c = flat & 63;
            tl[tt * 65 + c + 0] = v.x;
            tl[tt * 65 + c + 1] = v.y;
            tl[tt * 65 + c + 2] = v.z;
            tl[tt * 65 + c + 3] = v.w;
        }
        __syncthreads();
        const int lane = t256 & 63, w4 = t256 >> 6;
        for (int cc = w4; cc < 64; cc += 4) {
            xT[((size_t)(n * 64 + cc)) * T + t0 + lane] = __float2half(tl[lane * 65 + cc]);
        }
    }
}

// ---------------- kernel 2: Toeplitz-block MFMA conv, 4 waves/block ----------------
// Out_sl[16A+b] = sum_k W_sl[b][k-32*CLO] * xsh[16A+k].
// Block = 1 row, 4 waves: wh=w&1 picks the column half (A-cols [64wh,64wh+64)),
// wp=w>>1 picks the chunk half ([0,85) vs [85,169)). Both halves preserve the
// alive-prefix property. wp=1 partial f32 accs are reduced into wp=0 through a
// DEDICATED f32 LDS buffer (NOT xsh — xsh is only 3720 floats; Round-2 bug).
template<int N, int DEPTH>
__device__ __forceinline__ void conv_seg(int c0, int c1,
                                         const _Float16* __restrict__ xb,
                                         const _Float16* const (&ap)[5],
                                         f32x4 (&acc)[5][4]) {
    half8 A[DEPTH][N];
    half8 B[DEPTH][4];
    #pragma unroll
    for (int d = 0; d < DEPTH; ++d) {
        const int ko = (c0 + d) << 5;
        #pragma unroll
        for (int sl = 0; sl < N; ++sl) A[d][sl] = *(const half8*)(ap[sl] + ko);
        #pragma unroll
        for (int j = 0; j < 4; ++j)   B[d][j]  = *(const half8*)(xb + 256 * j + ko);
    }
    int c = c0;
    for (; c + DEPTH <= c1; c += DEPTH) {
        #pragma unroll
        for (int d = 0; d < DEPTH; ++d) {
            #pragma unroll
            for (int sl = 0; sl < N; ++sl) {
                acc[sl][0] = __builtin_amdgcn_mfma_f32_16x16x32_f16(A[d][sl], B[d][0], acc[sl][0], 0, 0, 0);
                acc[sl][1] = __builtin_amdgcn_mfma_f32_16x16x32_f16(A[d][sl], B[d][1], acc[sl][1], 0, 0, 0);
                acc[sl][2] = __builtin_amdgcn_mfma_f32_16x16x32_f16(A[d][sl], B[d][2], acc[sl][2], 0, 0, 0);
                acc[sl][3] = __builtin_amdgcn_mfma_f32_16x16x32_f16(A[d][sl], B[d][3], acc[sl][3], 0, 0, 0);
            }
            const int ko = (c + DEPTH + d) << 5;   // prefetch (unclamped, memory-safe)
            #pragma unroll
            for (int sl = 0; sl < N; ++sl) A[d][sl] = *(const half8*)(ap[sl] + ko);
            #pragma unroll
            for (int j = 0; j < 4; ++j)   B[d][j]  = *(const half8*)(xb + 256 * j + ko);
        }
    }
    #pragma unroll
    for (int d = 0; d < DEPTH; ++d) {
        if (d < c1 - c) {
            #pragma unroll
            for (int sl = 0; sl < N; ++sl) {
                acc[sl][0] = __builtin_amdgcn_mfma_f32_16x16x32_f16(A[d][sl], B[d][0], acc[sl][0], 0, 0, 0);
                acc[sl][1] = __builtin_amdgcn_mfma_f32_16x16x32_f16(A[d][sl], B[d][1], acc[sl][1], 0, 0, 0);
                acc[sl][2] = __builtin_amdgcn_mfma_f32_16x16x32_f16(A[d][sl], B[d][2], acc[sl][2], 0, 0, 0);
                acc[sl][3] = __builtin_amdgcn_mfma_f32_16x16x32_f16(A[d][sl], B[d][3], acc[sl][3], 0, 0, 0);
            }
        }
    }
}

__global__ __launch_bounds__(256, 4) void cwt_conv_mfma(const __half* __restrict__ xT,
                                                        const __half* __restrict__ Wg,
                                                        __half* __restrict__ outT) {
    constexpr int KS2[5]   = {5408, 2720, 1248, 480, 64};
    constexpr int WOFFe[5] = {0, 86528, 130048, 150016, 157696};
    constexpr int CLOe[5]  = {0, 42, 65, 77, 83};
    constexpr int OS[5]    = {4, 3, 2, 1, 0};

    __shared__ _Float16 xsh[XSH_N];               // 14880 B
    __shared__ _Float16 ostage[2048];             // 4096 B (1024/wave, wh 0/1)
    __shared__ float    red[2][2][1088];          // 17408 B: [s_local][wh][lane*17+j*4+r]
    const int tid  = threadIdx.x;
    const int row  = blockIdx.x;
    const int nidx = row >> 6;                    // batch n
    const int cidx = row & 63;                    // channel c
    const int lane = tid & 63;
    const int w    = tid >> 6;                    // wave 0..3
    const int wh   = w & 1;                       // column half: A-cols [64wh, 64wh+64)
    const int wp   = w >> 1;                      // chunk half: [0,85) / [85,169)
    const int mcol = lane & 15;                   // A-frag: W row b;  B-frag: col n
    const int grp  = lane >> 4;                   // k-subgroup

    // ---- stage padded signal row (fp16), 256 threads ----
    {
        uint4* x4 = (uint4*)xsh;
        const uint4 z = make_uint4(0u, 0u, 0u, 0u);
        for (int i = tid; i < XSH_N / 8; i += 256)
            if (i < PADL2 / 8 || i >= (PADL2 + T) / 8) x4[i] = z;
        const uint4* src = (const uint4*)(xT + (size_t)row * T);
        x4[PADL2 / 8 + tid] = src[tid];
    }
    __syncthreads();

    // per-lane operand bases
    const _Float16* xb = xsh + 1024 * wh + 16 * mcol + 8 * grp;  // tiles at +0,+256,+512,+768
    const _Float16* ap[5];
    #pragma unroll
    for (int sl = 0; sl < 5; ++sl)
        ap[sl] = (const _Float16*)Wg + WOFFe[sl] + mcol * KS2[sl] + 8 * grp
                 - (CLOe[sl] << 5);

    f32x4 acc[5][4];
    #pragma unroll
    for (int sl = 0; sl < 5; ++sl)
        #pragma unroll
        for (int j = 0; j < 4; ++j)
            acc[sl][j] = (f32x4){0.f, 0.f, 0.f, 0.f};

    // constant-alive-count segments over the unified chunk axis, split by wp.
    // alive: 336:[0,169) 167:[42,127) 76:[65,104) 27:[77,92) 1:[83,85)
    if (wp == 0) {
        conv_seg<1,3>(  0,  42, xb, ap, acc);
        conv_seg<2,3>( 42,  65, xb, ap, acc);
        conv_seg<3,2>( 65,  77, xb, ap, acc);
        conv_seg<4,2>( 77,  83, xb, ap, acc);
        conv_seg<5,2>( 83,  85, xb, ap, acc);
    } else {
        conv_seg<4,2>( 85,  92, xb, ap, acc);
        conv_seg<3,2>( 92, 104, xb, ap, acc);
        conv_seg<2,3>(104, 127, xb, ap, acc);
        conv_seg<1,3>(127, 169, xb, ap, acc);
    }

    // ---- cross-pair reduction: wp1 -> wp0, f32, 2 scales per round ----
    // sl 4 (scale 1) lives entirely in wp0's [83,85): no reduction needed.
    #pragma unroll
    for (int rnd = 0; rnd < 2; ++rnd) {
        const int s0 = rnd * 2;
        if (wp == 1) {
            #pragma unroll
            for (int s = 0; s < 2; ++s)
                #pragma unroll
                for (int j = 0; j < 4; ++j)
                    #pragma unroll
                    for (int r = 0; r < 4; ++r)
                        red[s][wh][lane * 17 + j * 4 + r] = acc[s0 + s][j][r];
        }
        __syncthreads();
        if (wp == 0) {
            #pragma unroll
            for (int s = 0; s < 2; ++s)
                #pragma unroll
                for (int j = 0; j < 4; ++j)
                    #pragma unroll
                    for (int r = 0; r < 4; ++r)
                        acc[s0 + s][j][r] += red[s][wh][lane * 17 + j * 4 + r];
        }
        __syncthreads();
    }

    // ---- epilogue (wp==0 waves only): D col=lane&15 -> A-col n, row=grp*4+r -> b ----
    if (wp == 0) {
        _Float16* os = ostage + 1024 * wh;        // wave-local, no barrier needed
        #pragma unroll
        for (int sl = 0; sl < 5; ++sl) {
            #pragma unroll
            for (int j = 0; j < 4; ++j) {
                half4v h;
                #pragma unroll
                for (int r = 0; r < 4; ++r) h[r] = (_Float16)acc[sl][j][r];
                *(half4v*)(os + 256 * j + 16 * mcol + 4 * grp) = h;
            }
            half8 o0 = *(const half8*)(os + 16 * lane);
            half8 o1 = *(const half8*)(os + 16 * lane + 8);
            __half* ob = outT + ((size_t)(((nidx * 128 + 64 * wh + lane) * 64 + cidx) * 5 + OS[sl])) * 16;
            *(half8*)(ob)     = o0;
            *(half8*)(ob + 8) = o1;
        }
    }
}

// ---------------- kernel 3: outT2[n][tb][c][s][16] -> out[n][t][c][s] ----------------
__global__ __launch_bounds__(256) void cwt_fix(const __half* __restrict__ outT,
                                               float* __restrict__ out) {
    __shared__ float tile[16 * 320];              // [tt][c*5+s]
    const int b  = blockIdx.x;                    // 0..2047
    const int n  = b >> 7;
    const int tb = b & 127;
    const int tid = threadIdx.x;

    const uint4* src = (const uint4*)(outT + (size_t)(n * 128 + tb) * 5120);
    for (int i = tid; i < 640; i += 256) {
        uint4 v = src[i];                         // 8 halves: (c,s) fixed, tt0..tt0+7
        const __half* h = (const __half*)&v;
        const int h0  = i * 8;
        const int sg  = h0 >> 4;                  // c*5+s
        const int tt0 = h0 & 15;                  // 0 or 8
        #pragma unroll
        for (int k = 0; k < 8; ++k) tile[(tt0 + k) * 320 + sg] = __half2float(h[k]);
    }
    __syncthreads();
    float4* dst = (float4*)(out + (size_t)(n * 2048 + tb * 16) * 320);
    const float4* tl = (const float4*)tile;
    for (int k = tid; k < 1280; k += 256) dst[k] = tl[k];
}

// ---------------- launch ----------------
extern "C" void kernel_launch(void* const* d_in, const int* in_sizes, int n_in,
                              void* d_out, int out_size, void* d_ws, size_t ws_size,
                              hipStream_t stream) {
    const float* x = (const float*)d_in[0];
    float* out = (float*)d_out;
    char* ws = (char*)d_ws;

    __half* W    = (__half*)ws;
    __half* xT   = (__half*)(ws + WS_XT);
    __half* outT = (__half*)(ws + WS_OUTT);

    cwt_prep<<<144, 1024, 0, stream>>>(x, xT, W);
    cwt_conv_mfma<<<NROWS, 256, 0, stream>>>(xT, W, outT);
    cwt_fix<<<2048, 256, 0, stream>>>(outT, out);
}

// Round 5
// 192.788 us; speedup vs baseline: 1.0940x; 1.0940x over previous
//
#include <hip/hip_runtime.h>
#include <hip/hip_fp16.h>
#include <math.h>

// ---------------- problem constants ----------------
// x: (16, 2048, 64) f32  -> out: (16, 2048, 64, 5) f32
// scales = {1,27,76,167,336}; morlet int_psi, n=1024, [-8,8]
#define NB    16
#define T     2048
#define NC    64
#define NROWS (NB*NC)     // 1024
#define PADL2 2696        // left zero-pad (halves), mult of 8
#define XSH_N 7440        // 2696 + 2048 + right pad; max valid B index 7439

// Unified global-k chunk axis: chunk c covers k in [32c, 32c+32), c in [0,169).
//   sl:      0      1      2      3      4
//   scale:   336    167    76     27     1
//   CLO:     0      42     65     77     83
//   KS2:     5408   2720   1248   480    64     (=32*NCH, W row stride)
//   WOFF:    0      86528  130048 150016 157696
//   outslot: 4      3      2      1      0
// alive: 336:[0,169) 167:[42,127) 76:[65,104) 27:[77,92) 1:[83,85)

// ws layout (bytes):
//   0        : __half W[158720]                    (~310 KB)
//   512 KB   : __half xT[1024][2048]               (4 MB)
//   512KB+4MB: __half outT2[16][128][64][5][16]    (20 MB)  [n][tb][c][s][tt]
#define WS_XT    (1u<<19)
#define WS_OUTT  ((1u<<19) + (1u<<22))

typedef _Float16 half8  __attribute__((ext_vector_type(8)));
typedef _Float16 half4v __attribute__((ext_vector_type(4)));
typedef float    f32x4  __attribute__((ext_vector_type(4)));

// ---------------- kernel 1: W-build (blocks 0..15, one per diagonal bb) ----------------
//                 + transpose (blocks 16..143)   [verified round 4]
__global__ __launch_bounds__(1024) void cwt_prep(const float* __restrict__ x,
                                                 __half* __restrict__ xT,
                                                 __half* __restrict__ W) {
    __shared__ double ps[1024];
    __shared__ double sc[1024];
    __shared__ float  k32[1024];
    __shared__ float  tile4[4][64 * 65];
    const int tid = threadIdx.x;

    if (blockIdx.x < 16) {
        const int bb = blockIdx.x;
        constexpr int SCe[5]   = {336, 167, 76, 27, 1};
        constexpr int KS2[5]   = {5408, 2720, 1248, 480, 64};
        constexpr int WOFFe[5] = {0, 86528, 130048, 150016, 157696};
        constexpr int CLOe[5]  = {0, 42, 65, 77, 83};

        // zero-fill own rows only (19840 B per bb)
        {
            const uint4 z = make_uint4(0u, 0u, 0u, 0u);
            #pragma unroll
            for (int sl = 0; sl < 5; ++sl) {
                uint4* z4 = (uint4*)(W + WOFFe[sl] + bb * KS2[sl]);
                const int n8 = KS2[sl] / 8;
                for (int i = tid; i < n8; i += 1024) z4[i] = z;
            }
        }

        const double delta = 16.0 / 1023.0;
        double t = (tid == 1023) ? 8.0 : (-8.0 + delta * (double)tid);
        ps[tid] = exp(-0.5 * t * t) * cos(5.0 * t);
        __syncthreads();   // also orders the zero-fill before the scatter below

        double* a = ps; double* b = sc;
        for (int off = 1; off < 1024; off <<= 1) {
            double v = a[tid];
            if (tid >= off) v += a[tid - off];
            b[tid] = v;
            __syncthreads();
            double* tmp = a; a = b; b = tmp;
        }
        const double step = ((-8.0 + delta) + 8.0);   // NOT exactly 16/1023
        k32[tid] = (float)(a[tid] * step);
        __syncthreads();

        for (int sl = 0; sl < 5; ++sl) {
            const int s = SCe[sl];
            const int L = 16 * s + 1;
            const double c = (double)s * step;
            const float sq = (float)sqrt((double)s);
            const int posoff = PADL2 - 8 * s - 1;
            const int kb0 = posoff - 32 * CLOe[sl];
            __half* wb = W + WOFFe[sl];
            const int Ks = KS2[sl];
            for (int i = tid; i <= L; i += 1024) {
                float g; bool wr = true;
                if (i == 0) {
                    g = sq * k32[0];
                } else if (i == L) {
                    long long jl = (long long)((double)(L - 1) / c);
                    if (jl > 1023) jl = 1023;
                    g = -sq * k32[jl];
                } else {
                    long long j1 = (long long)((double)i / c);
                    long long j0 = (long long)((double)(i - 1) / c);
                    if (j1 > 1023) j1 = 1023;
                    if (j0 > 1023) j0 = 1023;
                    wr = (j1 > j0);
                    g = sq * (k32[j1] - k32[j0]);
                }
                if (wr) {
                    wb[bb * Ks + kb0 + i + bb] = __float2half(g);
                }
            }
        }
    } else {
        const int g    = tid >> 8;                // 0..3: tile within block
        const int t256 = tid & 255;
        const int ti   = (blockIdx.x - 16) * 4 + g;  // 0..511
        const int n    = ti >> 5;
        const int t0   = (ti & 31) << 6;
        float* tl = tile4[g];

        const float4* src = (const float4*)(x + ((size_t)(n * T + t0)) * NC);
        #pragma unroll
        for (int k = 0; k < 4; ++k) {
            float4 v = src[t256 + 256 * k];
            const int flat = (t256 + 256 * k) * 4;
            const int tt = flat >> 6, c = flat & 63;
            tl[tt * 65 + c + 0] = v.x;
            tl[tt * 65 + c + 1] = v.y;
            tl[tt * 65 + c + 2] = v.z;
            tl[tt * 65 + c + 3] = v.w;
        }
        __syncthreads();
        const int lane = t256 & 63, w4 = t256 >> 6;
        for (int cc = w4; cc < 64; cc += 4) {
            xT[((size_t)(n * 64 + cc)) * T + t0 + lane] = __float2half(tl[lane * 65 + cc]);
        }
    }
}

// ---------------- kernel 2: Toeplitz-block MFMA conv, column-split ----------------
// Out_sl[16A+b] = sum_k W_sl[b][k-32*CLO] * xsh[16A+k]  (k is A-group-relative).
// 2048 blocks = (row, col-half h). Block = 2 waves x J=2 B-tiles (32 A-groups of
// 16 cols per wave). vs round-2: J 4->2 halves acc+B regs (~100 VGPR, fits the
// 128 cap of (128,4) -> 4 waves/SIMD, 8 blocks/CU, 16 waves/CU). No reduction.
// A (W, L2-resident) traffic doubles - expected hidden under MFMA+LDS.
template<int N, int DEPTH>
__device__ __forceinline__ void conv_seg(int c0, int c1,
                                         const _Float16* __restrict__ xb,
                                         const _Float16* const (&ap)[5],
                                         f32x4 (&acc)[5][2]) {
    half8 A[DEPTH][N];
    half8 B[DEPTH][2];
    #pragma unroll
    for (int d = 0; d < DEPTH; ++d) {
        const int ko = (c0 + d) << 5;
        #pragma unroll
        for (int sl = 0; sl < N; ++sl) A[d][sl] = *(const half8*)(ap[sl] + ko);
        #pragma unroll
        for (int j = 0; j < 2; ++j)   B[d][j]  = *(const half8*)(xb + 256 * j + ko);
    }
    int c = c0;
    for (; c + DEPTH <= c1; c += DEPTH) {
        #pragma unroll
        for (int d = 0; d < DEPTH; ++d) {
            #pragma unroll
            for (int sl = 0; sl < N; ++sl) {
                acc[sl][0] = __builtin_amdgcn_mfma_f32_16x16x32_f16(A[d][sl], B[d][0], acc[sl][0], 0, 0, 0);
                acc[sl][1] = __builtin_amdgcn_mfma_f32_16x16x32_f16(A[d][sl], B[d][1], acc[sl][1], 0, 0, 0);
            }
            const int ko = (c + DEPTH + d) << 5;   // prefetch (unclamped, memory-safe:
            #pragma unroll                         // stays inside xsh+ostage / W+xT)
            for (int sl = 0; sl < N; ++sl) A[d][sl] = *(const half8*)(ap[sl] + ko);
            #pragma unroll
            for (int j = 0; j < 2; ++j)   B[d][j]  = *(const half8*)(xb + 256 * j + ko);
        }
    }
    #pragma unroll
    for (int d = 0; d < DEPTH; ++d) {
        if (d < c1 - c) {
            #pragma unroll
            for (int sl = 0; sl < N; ++sl) {
                acc[sl][0] = __builtin_amdgcn_mfma_f32_16x16x32_f16(A[d][sl], B[d][0], acc[sl][0], 0, 0, 0);
                acc[sl][1] = __builtin_amdgcn_mfma_f32_16x16x32_f16(A[d][sl], B[d][1], acc[sl][1], 0, 0, 0);
            }
        }
    }
}

__global__ __launch_bounds__(128, 4) void cwt_conv_mfma(const __half* __restrict__ xT,
                                                        const __half* __restrict__ Wg,
                                                        __half* __restrict__ outT) {
    constexpr int KS2[5]   = {5408, 2720, 1248, 480, 64};
    constexpr int WOFFe[5] = {0, 86528, 130048, 150016, 157696};
    constexpr int CLOe[5]  = {0, 42, 65, 77, 83};
    constexpr int OS[5]    = {4, 3, 2, 1, 0};

    __shared__ _Float16 xsh[XSH_N];               // 14880 B
    __shared__ _Float16 ostage[1024];             // 2048 B (512/wave)
    const int tid  = threadIdx.x;
    const int bid  = blockIdx.x;
    const int row  = bid >> 1;                    // signal row (n,c)
    const int h    = bid & 1;                     // column half: A-groups [64h, 64h+64)
    const int nidx = row >> 6;                    // batch n
    const int cidx = row & 63;                    // channel c
    const int lane = tid & 63;
    const int w    = tid >> 6;                    // wave 0/1
    const int mcol = lane & 15;                   // A-frag: W row b;  B-frag: col n
    const int grp  = lane >> 4;                   // k-subgroup

    // ---- stage padded signal row (fp16), 128 threads [round-2 verified] ----
    {
        uint4* x4 = (uint4*)xsh;
        const uint4 z = make_uint4(0u, 0u, 0u, 0u);
        for (int i = tid; i < XSH_N / 8; i += 128)
            if (i < PADL2 / 8 || i >= (PADL2 + T) / 8) x4[i] = z;
        const uint4* src = (const uint4*)(xT + (size_t)row * T);
        x4[PADL2 / 8 + tid] = src[tid];
        x4[PADL2 / 8 + 128 + tid] = src[128 + tid];
    }
    __syncthreads();

    // per-lane operand bases; wave covers A-groups g0..g0+31 (2 B-tiles of 16)
    const int g0 = 64 * h + 32 * w;
    const _Float16* xb = xsh + 16 * g0 + 16 * mcol + 8 * grp;   // tiles at +0, +256
    const _Float16* ap[5];
    #pragma unroll
    for (int sl = 0; sl < 5; ++sl)
        ap[sl] = (const _Float16*)Wg + WOFFe[sl] + mcol * KS2[sl] + 8 * grp
                 - (CLOe[sl] << 5);

    f32x4 acc[5][2];
    #pragma unroll
    for (int sl = 0; sl < 5; ++sl)
        #pragma unroll
        for (int j = 0; j < 2; ++j)
            acc[sl][j] = (f32x4){0.f, 0.f, 0.f, 0.f};

    // constant-alive-count segments over the unified chunk axis
    // alive: 336:[0,169) 167:[42,127) 76:[65,104) 27:[77,92) 1:[83,85)
    conv_seg<1,3>(  0,  42, xb, ap, acc);
    conv_seg<2,3>( 42,  65, xb, ap, acc);
    conv_seg<3,2>( 65,  77, xb, ap, acc);
    conv_seg<4,2>( 77,  83, xb, ap, acc);
    conv_seg<5,2>( 83,  85, xb, ap, acc);
    conv_seg<4,2>( 85,  92, xb, ap, acc);
    conv_seg<3,2>( 92, 104, xb, ap, acc);
    conv_seg<2,3>(104, 127, xb, ap, acc);
    conv_seg<1,3>(127, 169, xb, ap, acc);

    // ---- epilogue: D col=mcol -> B-col n, row=grp*4+r -> b; local t' = 256j+16n+b ----
    // outT2 [n][tb][c][s][16]: wave covers tb = g0 .. g0+31; lane l: tb-local l>>1,
    // tt-half 8*(l&1).
    _Float16* os = ostage + 512 * w;              // wave-local, no barrier needed
    #pragma unroll
    for (int sl = 0; sl < 5; ++sl) {
        #pragma unroll
        for (int j = 0; j < 2; ++j) {
            half4v hv;
            #pragma unroll
            for (int r = 0; r < 4; ++r) hv[r] = (_Float16)acc[sl][j][r];
            *(half4v*)(os + 256 * j + 16 * mcol + 4 * grp) = hv;
        }
        half8 o = *(const half8*)(os + 8 * lane);
        const int tb = g0 + (lane >> 1);
        __half* ob = outT + ((size_t)(((nidx * 128 + tb) * 64 + cidx) * 5 + OS[sl])) * 16
                     + 8 * (lane & 1);
        *(half8*)(ob) = o;
    }
}

// ---------------- kernel 3: outT2[n][tb][c][s][16] -> out[n][t][c][s] ----------------
__global__ __launch_bounds__(256) void cwt_fix(const __half* __restrict__ outT,
                                               float* __restrict__ out) {
    __shared__ float tile[16 * 320];              // [tt][c*5+s]
    const int b  = blockIdx.x;                    // 0..2047
    const int n  = b >> 7;
    const int tb = b & 127;
    const int tid = threadIdx.x;

    const uint4* src = (const uint4*)(outT + (size_t)(n * 128 + tb) * 5120);
    for (int i = tid; i < 640; i += 256) {
        uint4 v = src[i];                         // 8 halves: (c,s) fixed, tt0..tt0+7
        const __half* h = (const __half*)&v;
        const int h0  = i * 8;
        const int sg  = h0 >> 4;                  // c*5+s
        const int tt0 = h0 & 15;                  // 0 or 8
        #pragma unroll
        for (int k = 0; k < 8; ++k) tile[(tt0 + k) * 320 + sg] = __half2float(h[k]);
    }
    __syncthreads();
    float4* dst = (float4*)(out + (size_t)(n * 2048 + tb * 16) * 320);
    const float4* tl = (const float4*)tile;
    for (int k = tid; k < 1280; k += 256) dst[k] = tl[k];
}

// ---------------- launch ----------------
extern "C" void kernel_launch(void* const* d_in, const int* in_sizes, int n_in,
                              void* d_out, int out_size, void* d_ws, size_t ws_size,
                              hipStream_t stream) {
    const float* x = (const float*)d_in[0];
    float* out = (float*)d_out;
    char* ws = (char*)d_ws;

    __half* W    = (__half*)ws;
    __half* xT   = (__half*)(ws + WS_XT);
    __half* outT = (__half*)(ws + WS_OUTT);

    cwt_prep<<<144, 1024, 0, stream>>>(x, xT, W);
    cwt_conv_mfma<<<2 * NROWS, 128, 0, stream>>>(xT, W, outT);
    cwt_fix<<<2048, 256, 0, stream>>>(outT, out);
}

// Round 6
// 190.357 us; speedup vs baseline: 1.1080x; 1.0128x over previous
//
#include <hip/hip_runtime.h>
#include <hip/hip_fp16.h>
#include <math.h>

// ---------------- problem constants ----------------
// x: (16, 2048, 64) f32  -> out: (16, 2048, 64, 5) f32
// scales = {1,27,76,167,336}; morlet int_psi, n=1024, [-8,8]
#define NB    16
#define T     2048
#define NC    64
#define NROWS (NB*NC)     // 1024
#define PADL2 2696        // left zero-pad (halves), mult of 8
#define XSH_N 7440        // 2696 + 2048 + right pad; max valid B index 7439

// Unified global-k chunk axis: chunk c covers k in [32c, 32c+32), c in [0,169).
//   sl:      0      1      2      3      4
//   scale:   336    167    76     27     1
//   CLO:     0      42     65     77     83
//   KS2:     5408   2720   1248   480    64     (=32*NCH, W row stride)
//   WOFF:    0      86528  130048 150016 157696
//   outslot: 4      3      2      1      0
// alive: 336:[0,169) 167:[42,127) 76:[65,104) 27:[77,92) 1:[83,85)

// ws layout (bytes):
//   0        : __half W[158720]                    (~310 KB)
//   512 KB   : __half xT[1024][2048]               (4 MB)
//   512KB+4MB: __half outT2[16][128][64][5][16]    (20 MB)  [n][tb][c][s][tt]
#define WS_XT    (1u<<19)
#define WS_OUTT  ((1u<<19) + (1u<<22))

typedef _Float16 half8  __attribute__((ext_vector_type(8)));
typedef _Float16 half4v __attribute__((ext_vector_type(4)));
typedef float    f32x4  __attribute__((ext_vector_type(4)));

// ---------------- kernel 1: W-build (blocks 0..15, one per diagonal bb) ----------------
//                 + transpose (blocks 16..143)   [verified rounds 4/5]
__global__ __launch_bounds__(1024) void cwt_prep(const float* __restrict__ x,
                                                 __half* __restrict__ xT,
                                                 __half* __restrict__ W) {
    __shared__ double ps[1024];
    __shared__ double sc[1024];
    __shared__ float  k32[1024];
    __shared__ float  tile4[4][64 * 65];
    const int tid = threadIdx.x;

    if (blockIdx.x < 16) {
        const int bb = blockIdx.x;
        constexpr int SCe[5]   = {336, 167, 76, 27, 1};
        constexpr int KS2[5]   = {5408, 2720, 1248, 480, 64};
        constexpr int WOFFe[5] = {0, 86528, 130048, 150016, 157696};
        constexpr int CLOe[5]  = {0, 42, 65, 77, 83};

        // zero-fill own rows only (19840 B per bb)
        {
            const uint4 z = make_uint4(0u, 0u, 0u, 0u);
            #pragma unroll
            for (int sl = 0; sl < 5; ++sl) {
                uint4* z4 = (uint4*)(W + WOFFe[sl] + bb * KS2[sl]);
                const int n8 = KS2[sl] / 8;
                for (int i = tid; i < n8; i += 1024) z4[i] = z;
            }
        }

        const double delta = 16.0 / 1023.0;
        double t = (tid == 1023) ? 8.0 : (-8.0 + delta * (double)tid);
        ps[tid] = exp(-0.5 * t * t) * cos(5.0 * t);
        __syncthreads();   // also orders the zero-fill before the scatter below

        double* a = ps; double* b = sc;
        for (int off = 1; off < 1024; off <<= 1) {
            double v = a[tid];
            if (tid >= off) v += a[tid - off];
            b[tid] = v;
            __syncthreads();
            double* tmp = a; a = b; b = tmp;
        }
        const double step = ((-8.0 + delta) + 8.0);   // NOT exactly 16/1023
        k32[tid] = (float)(a[tid] * step);
        __syncthreads();

        for (int sl = 0; sl < 5; ++sl) {
            const int s = SCe[sl];
            const int L = 16 * s + 1;
            const double c = (double)s * step;
            const float sq = (float)sqrt((double)s);
            const int posoff = PADL2 - 8 * s - 1;
            const int kb0 = posoff - 32 * CLOe[sl];
            __half* wb = W + WOFFe[sl];
            const int Ks = KS2[sl];
            for (int i = tid; i <= L; i += 1024) {
                float g; bool wr = true;
                if (i == 0) {
                    g = sq * k32[0];
                } else if (i == L) {
                    long long jl = (long long)((double)(L - 1) / c);
                    if (jl > 1023) jl = 1023;
                    g = -sq * k32[jl];
                } else {
                    long long j1 = (long long)((double)i / c);
                    long long j0 = (long long)((double)(i - 1) / c);
                    if (j1 > 1023) j1 = 1023;
                    if (j0 > 1023) j0 = 1023;
                    wr = (j1 > j0);
                    g = sq * (k32[j1] - k32[j0]);
                }
                if (wr) {
                    wb[bb * Ks + kb0 + i + bb] = __float2half(g);
                }
            }
        }
    } else {
        const int g    = tid >> 8;                // 0..3: tile within block
        const int t256 = tid & 255;
        const int ti   = (blockIdx.x - 16) * 4 + g;  // 0..511
        const int n    = ti >> 5;
        const int t0   = (ti & 31) << 6;
        float* tl = tile4[g];

        const float4* src = (const float4*)(x + ((size_t)(n * T + t0)) * NC);
        #pragma unroll
        for (int k = 0; k < 4; ++k) {
            float4 v = src[t256 + 256 * k];
            const int flat = (t256 + 256 * k) * 4;
            const int tt = flat >> 6, c = flat & 63;
            tl[tt * 65 + c + 0] = v.x;
            tl[tt * 65 + c + 1] = v.y;
            tl[tt * 65 + c + 2] = v.z;
            tl[tt * 65 + c + 3] = v.w;
        }
        __syncthreads();
        const int lane = t256 & 63, w4 = t256 >> 6;
        for (int cc = w4; cc < 64; cc += 4) {
            xT[((size_t)(n * 64 + cc)) * T + t0 + lane] = __float2half(tl[lane * 65 + cc]);
        }
    }
}

// ---------------- kernel 2: Toeplitz-block MFMA conv, column-split ----------------
// Out_sl[16A+b] = sum_k W_sl[b][k-32*CLO] * xsh[16A+k]  (k is A-group-relative).
// 2048 blocks = (row, col-half h). Block = 2 waves x J=2 B-tiles (32 A-groups of
// 16 cols per wave). launch_bounds(128,3): VGPR cap 170 >> natural ~110 need
// (the (128,4) cap of 128 forced VGPR_Count=64 + inner-loop scratch spill:
// WRITE +8MB, MfmaUtil 14%, 111us — rounds 4/5 lesson). 12 waves/CU guaranteed,
// 16 if allocator lands <=128.
template<int N, int DEPTH>
__device__ __forceinline__ void conv_seg(int c0, int c1,
                                         const _Float16* __restrict__ xb,
                                         const _Float16* const (&ap)[5],
                                         f32x4 (&acc)[5][2]) {
    half8 A[DEPTH][N];
    half8 B[DEPTH][2];
    #pragma unroll
    for (int d = 0; d < DEPTH; ++d) {
        const int ko = (c0 + d) << 5;
        #pragma unroll
        for (int sl = 0; sl < N; ++sl) A[d][sl] = *(const half8*)(ap[sl] + ko);
        #pragma unroll
        for (int j = 0; j < 2; ++j)   B[d][j]  = *(const half8*)(xb + 256 * j + ko);
    }
    int c = c0;
    for (; c + DEPTH <= c1; c += DEPTH) {
        #pragma unroll
        for (int d = 0; d < DEPTH; ++d) {
            #pragma unroll
            for (int sl = 0; sl < N; ++sl) {
                acc[sl][0] = __builtin_amdgcn_mfma_f32_16x16x32_f16(A[d][sl], B[d][0], acc[sl][0], 0, 0, 0);
                acc[sl][1] = __builtin_amdgcn_mfma_f32_16x16x32_f16(A[d][sl], B[d][1], acc[sl][1], 0, 0, 0);
            }
            const int ko = (c + DEPTH + d) << 5;   // prefetch (unclamped, memory-safe:
            #pragma unroll                         // stays inside xsh+ostage / W+xT)
            for (int sl = 0; sl < N; ++sl) A[d][sl] = *(const half8*)(ap[sl] + ko);
            #pragma unroll
            for (int j = 0; j < 2; ++j)   B[d][j]  = *(const half8*)(xb + 256 * j + ko);
        }
    }
    #pragma unroll
    for (int d = 0; d < DEPTH; ++d) {
        if (d < c1 - c) {
            #pragma unroll
            for (int sl = 0; sl < N; ++sl) {
                acc[sl][0] = __builtin_amdgcn_mfma_f32_16x16x32_f16(A[d][sl], B[d][0], acc[sl][0], 0, 0, 0);
                acc[sl][1] = __builtin_amdgcn_mfma_f32_16x16x32_f16(A[d][sl], B[d][1], acc[sl][1], 0, 0, 0);
            }
        }
    }
}

__global__ __launch_bounds__(128, 3) void cwt_conv_mfma(const __half* __restrict__ xT,
                                                        const __half* __restrict__ Wg,
                                                        __half* __restrict__ outT) {
    constexpr int KS2[5]   = {5408, 2720, 1248, 480, 64};
    constexpr int WOFFe[5] = {0, 86528, 130048, 150016, 157696};
    constexpr int CLOe[5]  = {0, 42, 65, 77, 83};
    constexpr int OS[5]    = {4, 3, 2, 1, 0};

    __shared__ _Float16 xsh[XSH_N];               // 14880 B
    __shared__ _Float16 ostage[1024];             // 2048 B (512/wave)
    const int tid  = threadIdx.x;
    const int bid  = blockIdx.x;
    const int row  = bid >> 1;                    // signal row (n,c)
    const int h    = bid & 1;                     // column half: A-groups [64h, 64h+64)
    const int nidx = row >> 6;                    // batch n
    const int cidx = row & 63;                    // channel c
    const int lane = tid & 63;
    const int w    = tid >> 6;                    // wave 0/1
    const int mcol = lane & 15;                   // A-frag: W row b;  B-frag: col n
    const int grp  = lane >> 4;                   // k-subgroup

    // ---- stage padded signal row (fp16), 128 threads [round-2 verified] ----
    {
        uint4* x4 = (uint4*)xsh;
        const uint4 z = make_uint4(0u, 0u, 0u, 0u);
        for (int i = tid; i < XSH_N / 8; i += 128)
            if (i < PADL2 / 8 || i >= (PADL2 + T) / 8) x4[i] = z;
        const uint4* src = (const uint4*)(xT + (size_t)row * T);
        x4[PADL2 / 8 + tid] = src[tid];
        x4[PADL2 / 8 + 128 + tid] = src[128 + tid];
    }
    __syncthreads();

    // per-lane operand bases; wave covers A-groups g0..g0+31 (2 B-tiles of 16)
    const int g0 = 64 * h + 32 * w;
    const _Float16* xb = xsh + 16 * g0 + 16 * mcol + 8 * grp;   // tiles at +0, +256
    const _Float16* ap[5];
    #pragma unroll
    for (int sl = 0; sl < 5; ++sl)
        ap[sl] = (const _Float16*)Wg + WOFFe[sl] + mcol * KS2[sl] + 8 * grp
                 - (CLOe[sl] << 5);

    f32x4 acc[5][2];
    #pragma unroll
    for (int sl = 0; sl < 5; ++sl)
        #pragma unroll
        for (int j = 0; j < 2; ++j)
            acc[sl][j] = (f32x4){0.f, 0.f, 0.f, 0.f};

    // constant-alive-count segments over the unified chunk axis
    // alive: 336:[0,169) 167:[42,127) 76:[65,104) 27:[77,92) 1:[83,85)
    conv_seg<1,3>(  0,  42, xb, ap, acc);
    conv_seg<2,3>( 42,  65, xb, ap, acc);
    conv_seg<3,2>( 65,  77, xb, ap, acc);
    conv_seg<4,2>( 77,  83, xb, ap, acc);
    conv_seg<5,1>( 83,  85, xb, ap, acc);   // 2 chunks; DEPTH 1 shaves peak VGPR
    conv_seg<4,2>( 85,  92, xb, ap, acc);
    conv_seg<3,2>( 92, 104, xb, ap, acc);
    conv_seg<2,3>(104, 127, xb, ap, acc);
    conv_seg<1,3>(127, 169, xb, ap, acc);

    // ---- epilogue: D col=mcol -> B-col n, row=grp*4+r -> b; local t' = 256j+16n+b ----
    // outT2 [n][tb][c][s][16]: wave covers tb = g0 .. g0+31; lane l: tb-local l>>1,
    // tt-half 8*(l&1).
    _Float16* os = ostage + 512 * w;              // wave-local, no barrier needed
    #pragma unroll
    for (int sl = 0; sl < 5; ++sl) {
        #pragma unroll
        for (int j = 0; j < 2; ++j) {
            half4v hv;
            #pragma unroll
            for (int r = 0; r < 4; ++r) hv[r] = (_Float16)acc[sl][j][r];
            *(half4v*)(os + 256 * j + 16 * mcol + 4 * grp) = hv;
        }
        half8 o = *(const half8*)(os + 8 * lane);
        const int tb = g0 + (lane >> 1);
        __half* ob = outT + ((size_t)(((nidx * 128 + tb) * 64 + cidx) * 5 + OS[sl])) * 16
                     + 8 * (lane & 1);
        *(half8*)(ob) = o;
    }
}

// ---------------- kernel 3: outT2[n][tb][c][s][16] -> out[n][t][c][s] ----------------
__global__ __launch_bounds__(256) void cwt_fix(const __half* __restrict__ outT,
                                               float* __restrict__ out) {
    __shared__ float tile[16 * 320];              // [tt][c*5+s]
    const int b  = blockIdx.x;                    // 0..2047
    const int n  = b >> 7;
    const int tb = b & 127;
    const int tid = threadIdx.x;

    const uint4* src = (const uint4*)(outT + (size_t)(n * 128 + tb) * 5120);
    for (int i = tid; i < 640; i += 256) {
        uint4 v = src[i];                         // 8 halves: (c,s) fixed, tt0..tt0+7
        const __half* h = (const __half*)&v;
        const int h0  = i * 8;
        const int sg  = h0 >> 4;                  // c*5+s
        const int tt0 = h0 & 15;                  // 0 or 8
        #pragma unroll
        for (int k = 0; k < 8; ++k) tile[(tt0 + k) * 320 + sg] = __half2float(h[k]);
    }
    __syncthreads();
    float4* dst = (float4*)(out + (size_t)(n * 2048 + tb * 16) * 320);
    const float4* tl = (const float4*)tile;
    for (int k = tid; k < 1280; k += 256) dst[k] = tl[k];
}

// ---------------- launch ----------------
extern "C" void kernel_launch(void* const* d_in, const int* in_sizes, int n_in,
                              void* d_out, int out_size, void* d_ws, size_t ws_size,
                              hipStream_t stream) {
    const float* x = (const float*)d_in[0];
    float* out = (float*)d_out;
    char* ws = (char*)d_ws;

    __half* W    = (__half*)ws;
    __half* xT   = (__half*)(ws + WS_XT);
    __half* outT = (__half*)(ws + WS_OUTT);

    cwt_prep<<<144, 1024, 0, stream>>>(x, xT, W);
    cwt_conv_mfma<<<2 * NROWS, 128, 0, stream>>>(xT, W, outT);
    cwt_fix<<<2048, 256, 0, stream>>>(outT, out);
}

// Round 9
// 145.517 us; speedup vs baseline: 1.4494x; 1.3081x over previous
//
#include <hip/hip_runtime.h>
#include <hip/hip_fp16.h>
#include <math.h>

// ---------------- problem constants ----------------
// x: (16, 2048, 64) f32  -> out: (16, 2048, 64, 5) f32
// scales = {1,27,76,167,336}; morlet int_psi, n=1024, [-8,8]
#define NB    16
#define T     2048
#define NC    64
#define NROWS (NB*NC)     // 1024
#define PADL2 2696        // left zero-pad (halves), mult of 8
#define XSH_N 7440        // 2696 + 2048 + right pad; max valid B index 7439

// Unified global-k chunk axis: chunk c covers k in [32c, 32c+32), c in [0,169).
//   sl:      0      1      2      3      4
//   scale:   336    167    76     27     1
//   CLO:     0      42     65     77     83
//   KS2:     5408   2720   1248   480    64     (=32*NCH, W row stride)
//   WOFF:    0      86528  130048 150016 157696
//   outslot: 4      3      2      1      0
// alive: 336:[0,169) 167:[42,127) 76:[65,104) 27:[77,92) 1:[83,85)

// ws layout (bytes):
//   0        : __half W[158720]                    (~310 KB)
//   512 KB   : __half xT[1024][2048]               (4 MB)
//   512KB+4MB: __half outT2[16][128][64][5][16]    (20 MB)  [n][tb][c][s][tt]
#define WS_XT    (1u<<19)
#define WS_OUTT  ((1u<<19) + (1u<<22))

typedef _Float16 half8  __attribute__((ext_vector_type(8)));
typedef _Float16 half4v __attribute__((ext_vector_type(4)));
typedef float    f32x4  __attribute__((ext_vector_type(4)));

// ---------------- kernel 1: W-build (blocks 0..15, one per diagonal bb) ----------------
//                 + transpose (blocks 16..143)   [verified rounds 4/5/6]
__global__ __launch_bounds__(1024) void cwt_prep(const float* __restrict__ x,
                                                 __half* __restrict__ xT,
                                                 __half* __restrict__ W) {
    __shared__ double ps[1024];
    __shared__ double sc[1024];
    __shared__ float  k32[1024];
    __shared__ float  tile4[4][64 * 65];
    const int tid = threadIdx.x;

    if (blockIdx.x < 16) {
        const int bb = blockIdx.x;
        constexpr int SCe[5]   = {336, 167, 76, 27, 1};
        constexpr int KS2[5]   = {5408, 2720, 1248, 480, 64};
        constexpr int WOFFe[5] = {0, 86528, 130048, 150016, 157696};
        constexpr int CLOe[5]  = {0, 42, 65, 77, 83};

        // zero-fill own rows only (19840 B per bb)
        {
            const uint4 z = make_uint4(0u, 0u, 0u, 0u);
            #pragma unroll
            for (int sl = 0; sl < 5; ++sl) {
                uint4* z4 = (uint4*)(W + WOFFe[sl] + bb * KS2[sl]);
                const int n8 = KS2[sl] / 8;
                for (int i = tid; i < n8; i += 1024) z4[i] = z;
            }
        }

        const double delta = 16.0 / 1023.0;
        double t = (tid == 1023) ? 8.0 : (-8.0 + delta * (double)tid);
        ps[tid] = exp(-0.5 * t * t) * cos(5.0 * t);
        __syncthreads();   // also orders the zero-fill before the scatter below

        double* a = ps; double* b = sc;
        for (int off = 1; off < 1024; off <<= 1) {
            double v = a[tid];
            if (tid >= off) v += a[tid - off];
            b[tid] = v;
            __syncthreads();
            double* tmp = a; a = b; b = tmp;
        }
        const double step = ((-8.0 + delta) + 8.0);   // NOT exactly 16/1023
        k32[tid] = (float)(a[tid] * step);
        __syncthreads();

        for (int sl = 0; sl < 5; ++sl) {
            const int s = SCe[sl];
            const int L = 16 * s + 1;
            const double c = (double)s * step;
            const float sq = (float)sqrt((double)s);
            const int posoff = PADL2 - 8 * s - 1;
            const int kb0 = posoff - 32 * CLOe[sl];
            __half* wb = W + WOFFe[sl];
            const int Ks = KS2[sl];
            for (int i = tid; i <= L; i += 1024) {
                float g; bool wr = true;
                if (i == 0) {
                    g = sq * k32[0];
                } else if (i == L) {
                    long long jl = (long long)((double)(L - 1) / c);
                    if (jl > 1023) jl = 1023;
                    g = -sq * k32[jl];
                } else {
                    long long j1 = (long long)((double)i / c);
                    long long j0 = (long long)((double)(i - 1) / c);
                    if (j1 > 1023) j1 = 1023;
                    if (j0 > 1023) j0 = 1023;
                    wr = (j1 > j0);
                    g = sq * (k32[j1] - k32[j0]);
                }
                if (wr) {
                    wb[bb * Ks + kb0 + i + bb] = __float2half(g);
                }
            }
        }
    } else {
        const int g    = tid >> 8;                // 0..3: tile within block
        const int t256 = tid & 255;
        const int ti   = (blockIdx.x - 16) * 4 + g;  // 0..511
        const int n    = ti >> 5;
        const int t0   = (ti & 31) << 6;
        float* tl = tile4[g];

        const float4* src = (const float4*)(x + ((size_t)(n * T + t0)) * NC);
        #pragma unroll
        for (int k = 0; k < 4; ++k) {
            float4 v = src[t256 + 256 * k];
            const int flat = (t256 + 256 * k) * 4;
            const int tt = flat >> 6, c = flat & 63;
            tl[tt * 65 + c + 0] = v.x;
            tl[tt * 65 + c + 1] = v.y;
            tl[tt * 65 + c + 2] = v.z;
            tl[tt * 65 + c + 3] = v.w;
        }
        __syncthreads();
        const int lane = t256 & 63, w4 = t256 >> 6;
        for (int cc = w4; cc < 64; cc += 4) {
            xT[((size_t)(n * 64 + cc)) * T + t0 + lane] = __float2half(tl[lane * 65 + cc]);
        }
    }
}

// ---------------- kernel 2: Toeplitz-block MFMA conv, 4 waves/block, k-split ----------------
// Out_sl[16A+b] = sum_k W_sl[b][k-32*CLO] * xsh[16A+k].
// Round-4 structure (verified correct): wh=w&1 col-half (J=4 B-tiles/wave),
// wp=w>>1 k-half ([0,85) vs [85,169)); wp1 partials reduced into wp0 via
// dedicated f32 LDS buffer. ONLY change vs round 4: launch_bounds (256,4) ->
// (256,2). The min-waves=4 clause capped VGPR at 128 -> scratch spill
// (VGPR_Count=64, WRITE +8MB, MfmaUtil 14%). Cap 256 >> natural ~150-180 need;
// J=4 keeps 4 MFMAs per A-load (the arithmetic intensity J=2 lost in rounds 5/6).
template<int N, int DEPTH>
__device__ __forceinline__ void conv_seg(int c0, int c1,
                                         const _Float16* __restrict__ xb,
                                         const _Float16* const (&ap)[5],
                                         f32x4 (&acc)[5][4]) {
    half8 A[DEPTH][N];
    half8 B[DEPTH][4];
    #pragma unroll
    for (int d = 0; d < DEPTH; ++d) {
        const int ko = (c0 + d) << 5;
        #pragma unroll
        for (int sl = 0; sl < N; ++sl) A[d][sl] = *(const half8*)(ap[sl] + ko);
        #pragma unroll
        for (int j = 0; j < 4; ++j)   B[d][j]  = *(const half8*)(xb + 256 * j + ko);
    }
    int c = c0;
    for (; c + DEPTH <= c1; c += DEPTH) {
        #pragma unroll
        for (int d = 0; d < DEPTH; ++d) {
            #pragma unroll
            for (int sl = 0; sl < N; ++sl) {
                acc[sl][0] = __builtin_amdgcn_mfma_f32_16x16x32_f16(A[d][sl], B[d][0], acc[sl][0], 0, 0, 0);
                acc[sl][1] = __builtin_amdgcn_mfma_f32_16x16x32_f16(A[d][sl], B[d][1], acc[sl][1], 0, 0, 0);
                acc[sl][2] = __builtin_amdgcn_mfma_f32_16x16x32_f16(A[d][sl], B[d][2], acc[sl][2], 0, 0, 0);
                acc[sl][3] = __builtin_amdgcn_mfma_f32_16x16x32_f16(A[d][sl], B[d][3], acc[sl][3], 0, 0, 0);
            }
            const int ko = (c + DEPTH + d) << 5;   // prefetch (unclamped, memory-safe)
            #pragma unroll
            for (int sl = 0; sl < N; ++sl) A[d][sl] = *(const half8*)(ap[sl] + ko);
            #pragma unroll
            for (int j = 0; j < 4; ++j)   B[d][j]  = *(const half8*)(xb + 256 * j + ko);
        }
    }
    #pragma unroll
    for (int d = 0; d < DEPTH; ++d) {
        if (d < c1 - c) {
            #pragma unroll
            for (int sl = 0; sl < N; ++sl) {
                acc[sl][0] = __builtin_amdgcn_mfma_f32_16x16x32_f16(A[d][sl], B[d][0], acc[sl][0], 0, 0, 0);
                acc[sl][1] = __builtin_amdgcn_mfma_f32_16x16x32_f16(A[d][sl], B[d][1], acc[sl][1], 0, 0, 0);
                acc[sl][2] = __builtin_amdgcn_mfma_f32_16x16x32_f16(A[d][sl], B[d][2], acc[sl][2], 0, 0, 0);
                acc[sl][3] = __builtin_amdgcn_mfma_f32_16x16x32_f16(A[d][sl], B[d][3], acc[sl][3], 0, 0, 0);
            }
        }
    }
}

__global__ __launch_bounds__(256, 2) void cwt_conv_mfma(const __half* __restrict__ xT,
                                                        const __half* __restrict__ Wg,
                                                        __half* __restrict__ outT) {
    constexpr int KS2[5]   = {5408, 2720, 1248, 480, 64};
    constexpr int WOFFe[5] = {0, 86528, 130048, 150016, 157696};
    constexpr int CLOe[5]  = {0, 42, 65, 77, 83};
    constexpr int OS[5]    = {4, 3, 2, 1, 0};

    __shared__ _Float16 xsh[XSH_N];               // 14880 B
    __shared__ _Float16 ostage[2048];             // 4096 B (1024/wave, wh 0/1)
    __shared__ float    red[2][2][1088];          // 17408 B: [s_local][wh][lane*17+j*4+r]
    const int tid  = threadIdx.x;
    const int row  = blockIdx.x;
    const int nidx = row >> 6;                    // batch n
    const int cidx = row & 63;                    // channel c
    const int lane = tid & 63;
    const int w    = tid >> 6;                    // wave 0..3
    const int wh   = w & 1;                       // column half: A-cols [64wh, 64wh+64)
    const int wp   = w >> 1;                      // chunk half: [0,85) / [85,169)
    const int mcol = lane & 15;                   // A-frag: W row b;  B-frag: col n
    const int grp  = lane >> 4;                   // k-subgroup

    // ---- stage padded signal row (fp16), 256 threads ----
    {
        uint4* x4 = (uint4*)xsh;
        const uint4 z = make_uint4(0u, 0u, 0u, 0u);
        for (int i = tid; i < XSH_N / 8; i += 256)
            if (i < PADL2 / 8 || i >= (PADL2 + T) / 8) x4[i] = z;
        const uint4* src = (const uint4*)(xT + (size_t)row * T);
        x4[PADL2 / 8 + tid] = src[tid];
    }
    __syncthreads();

    // per-lane operand bases
    const _Float16* xb = xsh + 1024 * wh + 16 * mcol + 8 * grp;  // tiles at +0,+256,+512,+768
    const _Float16* ap[5];
    #pragma unroll
    for (int sl = 0; sl < 5; ++sl)
        ap[sl] = (const _Float16*)Wg + WOFFe[sl] + mcol * KS2[sl] + 8 * grp
                 - (CLOe[sl] << 5);

    f32x4 acc[5][4];
    #pragma unroll
    for (int sl = 0; sl < 5; ++sl)
        #pragma unroll
        for (int j = 0; j < 4; ++j)
            acc[sl][j] = (f32x4){0.f, 0.f, 0.f, 0.f};

    // constant-alive-count segments over the unified chunk axis, split by wp.
    // alive: 336:[0,169) 167:[42,127) 76:[65,104) 27:[77,92) 1:[83,85)
    if (wp == 0) {
        conv_seg<1,3>(  0,  42, xb, ap, acc);
        conv_seg<2,3>( 42,  65, xb, ap, acc);
        conv_seg<3,2>( 65,  77, xb, ap, acc);
        conv_seg<4,2>( 77,  83, xb, ap, acc);
        conv_seg<5,2>( 83,  85, xb, ap, acc);
    } else {
        conv_seg<4,2>( 85,  92, xb, ap, acc);
        conv_seg<3,2>( 92, 104, xb, ap, acc);
        conv_seg<2,3>(104, 127, xb, ap, acc);
        conv_seg<1,3>(127, 169, xb, ap, acc);
    }

    // ---- cross-pair reduction: wp1 -> wp0, f32, 2 scales per round ----
    // sl 4 (scale 1) lives entirely in wp0's [83,85): no reduction needed.
    #pragma unroll
    for (int rnd = 0; rnd < 2; ++rnd) {
        const int s0 = rnd * 2;
        if (wp == 1) {
            #pragma unroll
            for (int s = 0; s < 2; ++s)
                #pragma unroll
                for (int j = 0; j < 4; ++j)
                    #pragma unroll
                    for (int r = 0; r < 4; ++r)
                        red[s][wh][lane * 17 + j * 4 + r] = acc[s0 + s][j][r];
        }
        __syncthreads();
        if (wp == 0) {
            #pragma unroll
            for (int s = 0; s < 2; ++s)
                #pragma unroll
                for (int j = 0; j < 4; ++j)
                    #pragma unroll
                    for (int r = 0; r < 4; ++r)
                        acc[s0 + s][j][r] += red[s][wh][lane * 17 + j * 4 + r];
        }
        __syncthreads();
    }

    // ---- epilogue (wp==0 waves only): D col=lane&15 -> A-col n, row=grp*4+r -> b ----
    if (wp == 0) {
        _Float16* os = ostage + 1024 * wh;        // wave-local, no barrier needed
        #pragma unroll
        for (int sl = 0; sl < 5; ++sl) {
            #pragma unroll
            for (int j = 0; j < 4; ++j) {
                half4v h;
                #pragma unroll
                for (int r = 0; r < 4; ++r) h[r] = (_Float16)acc[sl][j][r];
                *(half4v*)(os + 256 * j + 16 * mcol + 4 * grp) = h;
            }
            half8 o0 = *(const half8*)(os + 16 * lane);
            half8 o1 = *(const half8*)(os + 16 * lane + 8);
            __half* ob = outT + ((size_t)(((nidx * 128 + 64 * wh + lane) * 64 + cidx) * 5 + OS[sl])) * 16;
            *(half8*)(ob)     = o0;
            *(half8*)(ob + 8) = o1;
        }
    }
}

// ---------------- kernel 3: outT2[n][tb][c][s][16] -> out[n][t][c][s] ----------------
__global__ __launch_bounds__(256) void cwt_fix(const __half* __restrict__ outT,
                                               float* __restrict__ out) {
    __shared__ float tile[16 * 320];              // [tt][c*5+s]
    const int b  = blockIdx.x;                    // 0..2047
    const int n  = b >> 7;
    const int tb = b & 127;
    const int tid = threadIdx.x;

    const uint4* src = (const uint4*)(outT + (size_t)(n * 128 + tb) * 5120);
    for (int i = tid; i < 640; i += 256) {
        uint4 v = src[i];                         // 8 halves: (c,s) fixed, tt0..tt0+7
        const __half* h = (const __half*)&v;
        const int h0  = i * 8;
        const int sg  = h0 >> 4;                  // c*5+s
        const int tt0 = h0 & 15;                  // 0 or 8
        #pragma unroll
        for (int k = 0; k < 8; ++k) tile[(tt0 + k) * 320 + sg] = __half2float(h[k]);
    }
    __syncthreads();
    float4* dst = (float4*)(out + (size_t)(n * 2048 + tb * 16) * 320);
    const float4* tl = (const float4*)tile;
    for (int k = tid; k < 1280; k += 256) dst[k] = tl[k];
}

// ---------------- launch ----------------
extern "C" void kernel_launch(void* const* d_in, const int* in_sizes, int n_in,
                              void* d_out, int out_size, void* d_ws, size_t ws_size,
                              hipStream_t stream) {
    const float* x = (const float*)d_in[0];
    float* out = (float*)d_out;
    char* ws = (char*)d_ws;

    __half* W    = (__half*)ws;
    __half* xT   = (__half*)(ws + WS_XT);
    __half* outT = (__half*)(ws + WS_OUTT);

    cwt_prep<<<144, 1024, 0, stream>>>(x, xT, W);
    cwt_conv_mfma<<<NROWS, 256, 0, stream>>>(xT, W, outT);
    cwt_fix<<<2048, 256, 0, stream>>>(outT, out);
}